// Round 1
// baseline (502.609 us; speedup 1.0000x reference)
//
#include <hip/hip_runtime.h>
#include <cmath>

// ---------------- problem constants ----------------
#define NLAYERS 100      // hidden layers (scan)
#define DIN     64       // input features
#define WDIM    100      // hidden width
#define NPAD    112      // padded N (7 tiles of 16)
#define NT      7        // n tiles
#define RT      2        // row tiles of 16 -> 32 rows per wave
#define ROWS    32
#define HSTR    116      // f32 LDS row stride (112 cols + 4 pad; 2-way banks only)

typedef _Float16 half8 __attribute__((ext_vector_type(8)));
typedef float    f32x4 __attribute__((ext_vector_type(4)));

// ---------------- workspace layout ----------------
#define WSH_LAYER_HALVES (NT * 4 * 64 * 8)               // 14336 halves per hidden layer
#define WSH_HALVES       (NLAYERS * WSH_LAYER_HALVES)    // 1,433,600
#define W0_HALVES        (NT * 2 * 64 * 8)               // 7168 (input layer, K=64)
#define BPAD_FLOATS      ((NLAYERS + 1) * NPAD)          // 11312
#define OFF_BPAD_B       ((WSH_HALVES + W0_HALVES) * 2)  // bytes, 16-aligned
#define OFF_WOUT_B       (OFF_BPAD_B + BPAD_FLOATS * 4)  // bytes, 16-aligned
#define TOTAL_PREP       (WSH_HALVES + W0_HALVES + BPAD_FLOATS + NPAD)

// ============================================================
// Prep: shuffle weights into exact MFMA B-fragment order (f16),
// pad biases / W_out. Re-run every launch (ws is re-poisoned).
// B-frag for (nt,ks): lane(q=lane>>4,l15=lane&15), elem j ->
//   B[k = ks*32 + q*8 + j][n = nt*16 + l15]
// ============================================================
__global__ void actor_prep(const float* __restrict__ Win, const float* __restrict__ bin,
                           const float* __restrict__ Ws,  const float* __restrict__ bs,
                           const float* __restrict__ Wout,
                           _Float16* __restrict__ wsh, _Float16* __restrict__ w0sh,
                           float* __restrict__ bpad, float* __restrict__ woutp) {
    int t = blockIdx.x * 256 + threadIdx.x;
    if (t < WSH_HALVES) {                       // hidden-layer weights
        int j    = t & 7;
        int lane = (t >> 3) & 63;
        int ks   = (t >> 9) & 3;
        int rest = t >> 11;                     // l*7 + nt
        int nt   = rest % 7;
        int l    = rest / 7;
        int qq = lane >> 4, ll = lane & 15;
        int k = ks * 32 + qq * 8 + j;
        int n = nt * 16 + ll;
        float v = (k < WDIM && n < WDIM) ? Ws[(l * WDIM + k) * WDIM + n] : 0.f;
        wsh[t] = (_Float16)v;
        return;
    }
    int t2 = t - WSH_HALVES;
    if (t2 < W0_HALVES) {                       // input layer weights (K=64)
        int j    = t2 & 7;
        int lane = (t2 >> 3) & 63;
        int ks   = (t2 >> 9) & 1;
        int nt   = t2 >> 10;
        int qq = lane >> 4, ll = lane & 15;
        int k = ks * 32 + qq * 8 + j;
        int n = nt * 16 + ll;
        float v = (k < DIN && n < WDIM) ? Win[k * WDIM + n] : 0.f;
        w0sh[t2] = (_Float16)v;
        return;
    }
    int t3 = t2 - W0_HALVES;
    if (t3 < BPAD_FLOATS) {                     // padded biases: row 0 = b_in, rows 1..100 = bs
        int l = t3 / NPAD, c = t3 % NPAD;
        float v = 0.f;
        if (c < WDIM) v = (l == 0) ? bin[c] : bs[(l - 1) * WDIM + c];
        bpad[t3] = v;
        return;
    }
    int t4 = t3 - BPAD_FLOATS;
    if (t4 < NPAD) woutp[t4] = (t4 < WDIM) ? Wout[t4] : 0.f;
}

// split fp32 -> hi/lo fp16 pair (hi RNE, lo = residual; ~22 mantissa bits total)
__device__ __forceinline__ void split8(const float* __restrict__ p, half8& hi, half8& lo) {
    f32x4 u0 = *(const f32x4*)p;
    f32x4 u1 = *(const f32x4*)(p + 4);
#pragma unroll
    for (int e = 0; e < 4; ++e) {
        float v = u0[e];
        _Float16 h = (_Float16)v;
        hi[e] = h;
        lo[e] = (_Float16)(v - (float)h);
        float w = u1[e];
        _Float16 g = (_Float16)w;
        hi[e + 4] = g;
        lo[e + 4] = (_Float16)(w - (float)g);
    }
}

// ============================================================
// Main: one wave per block, 32 rows, whole network fused.
// h kept fp32 in LDS; per-layer: LDS->(hi,lo f16 A-frags),
// weights read as pre-shuffled global B-frags (L1/L2 hot),
// 2 MFMAs (hi,lo) per tile, fp32 accumulate, leaky+bias, back to LDS.
// No barriers: each wave owns its rows; same-wave DS ops are in-order.
// ============================================================
__global__ __launch_bounds__(64, 2)
void actor_main(const float* __restrict__ x,
                const _Float16* __restrict__ wsh,
                const _Float16* __restrict__ w0sh,
                const float* __restrict__ bpad,
                const float* __restrict__ woutp,
                const float* __restrict__ bout,
                float* __restrict__ out) {
    __shared__ float hlds[ROWS][HSTR];
    const int lane = threadIdx.x;
    const int q = lane >> 4, l15 = lane & 15;
    const int rowbase = blockIdx.x * ROWS;

    f32x4 acc[RT][NT];
    half8 bb[2][NT];                 // double-buffered B fragments (prefetch 1 k-step ahead)
    const f32x4 zero4 = {0.f, 0.f, 0.f, 0.f};
    const half8 zeroh = {0, 0, 0, 0, 0, 0, 0, 0};

#pragma unroll
    for (int rt = 0; rt < RT; ++rt)
#pragma unroll
        for (int nt = 0; nt < NT; ++nt) acc[rt][nt] = zero4;

    // preload input-layer ks=0 B frags
#pragma unroll
    for (int nt = 0; nt < NT; ++nt)
        bb[0][nt] = *(const half8*)(w0sh + ((nt * 2 + 0) * 64 + lane) * 8);

    // ---------------- layer 0: x @ W_in (K=64) ----------------
#pragma unroll
    for (int ks = 0; ks < 2; ++ks) {
        const int cur = ks & 1, nxt = cur ^ 1;
        if (ks == 0) {               // prefetch ks=1
#pragma unroll
            for (int nt = 0; nt < NT; ++nt)
                bb[nxt][nt] = *(const half8*)(w0sh + ((nt * 2 + 1) * 64 + lane) * 8);
        } else {                     // prefetch hidden layer 0, ks=0
#pragma unroll
            for (int nt = 0; nt < NT; ++nt)
                bb[nxt][nt] = *(const half8*)(wsh + ((nt * 4 + 0) * 64 + lane) * 8);
        }
#pragma unroll
        for (int rt = 0; rt < RT; ++rt) {
            half8 ahi, alo;
            split8(x + (rowbase + rt * 16 + l15) * DIN + ks * 32 + q * 8, ahi, alo);
#pragma unroll
            for (int nt = 0; nt < NT; ++nt) {
                acc[rt][nt] = __builtin_amdgcn_mfma_f32_16x16x32_f16(ahi, bb[cur][nt], acc[rt][nt], 0, 0, 0);
                acc[rt][nt] = __builtin_amdgcn_mfma_f32_16x16x32_f16(alo, bb[cur][nt], acc[rt][nt], 0, 0, 0);
            }
        }
    }
    // epilogue 0: bias + leaky -> LDS (cols 100..111 become exact zeros)
#pragma unroll
    for (int rt = 0; rt < RT; ++rt)
#pragma unroll
        for (int nt = 0; nt < NT; ++nt) {
            const int col = nt * 16 + l15;
            const float bbias = bpad[col];
#pragma unroll
            for (int r = 0; r < 4; ++r) {
                float v = acc[rt][nt][r] + bbias;
                v = fmaxf(v, 0.01f * v);          // leaky: max(x, 0.01x)
                hlds[rt * 16 + q * 4 + r][col] = v;
            }
        }

    // ---------------- 100 hidden layers (K=128 padded, ks=3 half-masked) ----------------
#pragma unroll 1
    for (int l = 0; l < NLAYERS; ++l) {
        const _Float16* wl = wsh + l * WSH_LAYER_HALVES;
        const _Float16* wlnext = wsh + (l < NLAYERS - 1 ? l + 1 : l) * WSH_LAYER_HALVES;
#pragma unroll
        for (int rt = 0; rt < RT; ++rt)
#pragma unroll
            for (int nt = 0; nt < NT; ++nt) acc[rt][nt] = zero4;

#pragma unroll
        for (int ks = 0; ks < 4; ++ks) {
            const int cur = ks & 1, nxt = cur ^ 1;
            // prefetch next k-step (or next layer's ks=0) B frags
            const _Float16* src = (ks < 3) ? (wl + ((0 * 4 + (ks + 1)) * 64 + lane) * 8)
                                           : (wlnext + ((0 * 4 + 0) * 64 + lane) * 8);
#pragma unroll
            for (int nt = 0; nt < NT; ++nt)
                bb[nxt][nt] = *(const half8*)(src + nt * 4 * 64 * 8);

#pragma unroll
            for (int rt = 0; rt < RT; ++rt) {
                half8 ahi, alo;
                if (ks == 3 && q >= 2) {          // k in [112,128): zero pad region (must mask!)
                    ahi = zeroh; alo = zeroh;
                } else {
                    split8(&hlds[rt * 16 + l15][ks * 32 + q * 8], ahi, alo);
                }
#pragma unroll
                for (int nt = 0; nt < NT; ++nt) {
                    acc[rt][nt] = __builtin_amdgcn_mfma_f32_16x16x32_f16(ahi, bb[cur][nt], acc[rt][nt], 0, 0, 0);
                    acc[rt][nt] = __builtin_amdgcn_mfma_f32_16x16x32_f16(alo, bb[cur][nt], acc[rt][nt], 0, 0, 0);
                }
            }
        }
        // epilogue: bias + leaky -> LDS (fp32, full precision carried between layers)
        const float* brow = bpad + (l + 1) * NPAD;
#pragma unroll
        for (int rt = 0; rt < RT; ++rt)
#pragma unroll
            for (int nt = 0; nt < NT; ++nt) {
                const int col = nt * 16 + l15;
                const float bbias = brow[col];
#pragma unroll
                for (int r = 0; r < 4; ++r) {
                    float v = acc[rt][nt][r] + bbias;
                    v = fmaxf(v, 0.01f * v);
                    hlds[rt * 16 + q * 4 + r][col] = v;
                }
            }
    }

    // ---------------- head: dot(h, W_out) + b_out, tanh, affine ----------------
    {
        const int row = lane >> 1, hf = lane & 1;   // 2 lanes per row, 56 cols each
        const float* hp = &hlds[row][hf * 56];
        const float* wp = woutp + hf * 56;
        float s = 0.f;
#pragma unroll
        for (int i = 0; i < 14; ++i) {
            f32x4 hv = *(const f32x4*)(hp + i * 4);
            f32x4 wv = *(const f32x4*)(wp + i * 4);
            s += hv[0] * wv[0] + hv[1] * wv[1] + hv[2] * wv[2] + hv[3] * wv[3];
        }
        s += __shfl_xor(s, 1);
        if (hf == 0) {
            float a = s + bout[0];
            float t = tanhf(a);
            out[rowbase + row] = t * 4.5f + 5.5f;   // (tanh+1)/2*9 + 1
        }
    }
}

extern "C" void kernel_launch(void* const* d_in, const int* in_sizes, int n_in,
                              void* d_out, int out_size, void* d_ws, size_t ws_size,
                              hipStream_t stream) {
    const float* x    = (const float*)d_in[0];
    const float* Win  = (const float*)d_in[1];
    const float* bin  = (const float*)d_in[2];
    const float* Ws   = (const float*)d_in[3];
    const float* bs   = (const float*)d_in[4];
    const float* Wout = (const float*)d_in[5];
    const float* bout = (const float*)d_in[6];
    float* out = (float*)d_out;

    char* ws = (char*)d_ws;
    _Float16* wsh  = (_Float16*)ws;
    _Float16* w0sh = wsh + WSH_HALVES;
    float* bpad  = (float*)(ws + OFF_BPAD_B);
    float* woutp = (float*)(ws + OFF_WOUT_B);

    hipLaunchKernelGGL(actor_prep, dim3((TOTAL_PREP + 255) / 256), dim3(256), 0, stream,
                       Win, bin, Ws, bs, Wout, wsh, w0sh, bpad, woutp);

    const int nrows = in_sizes[0] / DIN;   // 65536
    hipLaunchKernelGGL(actor_main, dim3(nrows / ROWS), dim3(64), 0, stream,
                       x, wsh, w0sh, bpad, woutp, bout, out);
}

// Round 3
// 483.034 us; speedup vs baseline: 1.0405x; 1.0405x over previous
//
#include <hip/hip_runtime.h>
#include <cmath>

// ---------------- problem constants ----------------
#define NLAYERS 100      // hidden layers (scan)
#define DIN     64       // input features
#define WDIM    100      // hidden width
#define NPAD    112      // padded N (7 tiles of 16)
#define NT      7        // n tiles
#define ROWS    16       // rows per wave (1 row-tile) -> 4096 waves = 4 waves/SIMD
#define HSTR    116      // f32 LDS row stride (112 cols + 4 pad; 2-way banks only)

typedef _Float16 half8 __attribute__((ext_vector_type(8)));
typedef __fp16   fp16x2 __attribute__((ext_vector_type(2)));   // cvt_pkrtz return type
typedef float    f32x4 __attribute__((ext_vector_type(4)));

// ---------------- workspace layout ----------------
#define WSH_LAYER_HALVES (NT * 4 * 64 * 8)               // 14336 halves per hidden layer
#define WSH_HALVES       (NLAYERS * WSH_LAYER_HALVES)    // 1,433,600
#define W0_HALVES        (NT * 2 * 64 * 8)               // 7168 (input layer, K=64)
#define BPAD_FLOATS      ((NLAYERS + 1) * NPAD)          // 11312
#define OFF_BPAD_B       ((WSH_HALVES + W0_HALVES) * 2)  // bytes, 16-aligned
#define OFF_WOUT_B       (OFF_BPAD_B + BPAD_FLOATS * 4)  // bytes, 16-aligned
#define TOTAL_PREP       (WSH_HALVES + W0_HALVES + BPAD_FLOATS + NPAD)

// ============================================================
// Prep: shuffle weights into exact MFMA B-fragment order (f16),
// pad biases / W_out. Re-run every launch (ws is re-poisoned).
// B-frag for (nt,ks): lane(q=lane>>4,l15=lane&15), elem j ->
//   B[k = ks*32 + q*8 + j][n = nt*16 + l15]
// ============================================================
__global__ void actor_prep(const float* __restrict__ Win, const float* __restrict__ bin,
                           const float* __restrict__ Ws,  const float* __restrict__ bs,
                           const float* __restrict__ Wout,
                           _Float16* __restrict__ wsh, _Float16* __restrict__ w0sh,
                           float* __restrict__ bpad, float* __restrict__ woutp) {
    int t = blockIdx.x * 256 + threadIdx.x;
    if (t < WSH_HALVES) {                       // hidden-layer weights
        int j    = t & 7;
        int lane = (t >> 3) & 63;
        int ks   = (t >> 9) & 3;
        int rest = t >> 11;                     // l*7 + nt
        int nt   = rest % 7;
        int l    = rest / 7;
        int qq = lane >> 4, ll = lane & 15;
        int k = ks * 32 + qq * 8 + j;
        int n = nt * 16 + ll;
        float v = (k < WDIM && n < WDIM) ? Ws[(l * WDIM + k) * WDIM + n] : 0.f;
        wsh[t] = (_Float16)v;
        return;
    }
    int t2 = t - WSH_HALVES;
    if (t2 < W0_HALVES) {                       // input layer weights (K=64)
        int j    = t2 & 7;
        int lane = (t2 >> 3) & 63;
        int ks   = (t2 >> 9) & 1;
        int nt   = t2 >> 10;
        int qq = lane >> 4, ll = lane & 15;
        int k = ks * 32 + qq * 8 + j;
        int n = nt * 16 + ll;
        float v = (k < DIN && n < WDIM) ? Win[k * WDIM + n] : 0.f;
        w0sh[t2] = (_Float16)v;
        return;
    }
    int t3 = t2 - W0_HALVES;
    if (t3 < BPAD_FLOATS) {                     // padded biases: row 0 = b_in, rows 1..100 = bs
        int l = t3 / NPAD, c = t3 % NPAD;
        float v = 0.f;
        if (c < WDIM) v = (l == 0) ? bin[c] : bs[(l - 1) * WDIM + c];
        bpad[t3] = v;
        return;
    }
    int t4 = t3 - BPAD_FLOATS;
    if (t4 < NPAD) woutp[t4] = (t4 < WDIM) ? Wout[t4] : 0.f;
}

// split fp32 -> hi/lo fp16 via packed RTZ cvt (hi RTZ, lo = residual RTZ).
// RTZ is safe: lo captures hi's rounding residual exactly up to lo's own
// rounding (~2^-21 rel) — invisible vs the 2^-12 f16-weight error floor.
__device__ __forceinline__ void split8(const float* __restrict__ p, half8& hi, half8& lo) {
    f32x4 u0 = *(const f32x4*)p;
    f32x4 u1 = *(const f32x4*)(p + 4);
    float v[8] = {u0[0], u0[1], u0[2], u0[3], u1[0], u1[1], u1[2], u1[3]};
#pragma unroll
    for (int e = 0; e < 8; e += 2) {
        fp16x2 h = __builtin_amdgcn_cvt_pkrtz(v[e], v[e + 1]);
        float r0 = v[e]     - (float)h[0];
        float r1 = v[e + 1] - (float)h[1];
        fp16x2 l = __builtin_amdgcn_cvt_pkrtz(r0, r1);
        hi[e] = (_Float16)h[0]; hi[e + 1] = (_Float16)h[1];
        lo[e] = (_Float16)l[0]; lo[e + 1] = (_Float16)l[1];
    }
}

// ============================================================
// Main: one wave per block, 16 rows, whole network fused.
// h kept fp32 in LDS; per-layer: LDS->(hi,lo f16 A-frags),
// weights read as pre-shuffled global B-frags (L1-hot: 28KB/layer,
// software-pipelined one k-step ahead), 2 MFMAs (hi,lo) per tile,
// fp32 accumulate, leaky+bias, back to LDS. No barriers (1 wave owns h).
// ROWS=16 -> 4096 waves = 4 waves/SIMD for MFMA/VALU pipe overlap.
// ============================================================
__global__ __launch_bounds__(64, 4)
void actor_main(const float* __restrict__ x,
                const _Float16* __restrict__ wsh,
                const _Float16* __restrict__ w0sh,
                const float* __restrict__ bpad,
                const float* __restrict__ woutp,
                const float* __restrict__ bout,
                float* __restrict__ out) {
    __shared__ float hlds[ROWS][HSTR];
    const int lane = threadIdx.x;
    const int q = lane >> 4, l15 = lane & 15;
    const int rowbase = blockIdx.x * ROWS;

    f32x4 acc[NT];
    half8 bb[2][NT];                 // double-buffered B fragments (prefetch 1 k-step ahead)
    const f32x4 zero4 = {0.f, 0.f, 0.f, 0.f};
    const half8 zeroh = {0, 0, 0, 0, 0, 0, 0, 0};

#pragma unroll
    for (int nt = 0; nt < NT; ++nt) acc[nt] = zero4;

    // preload input-layer ks=0 B frags
#pragma unroll
    for (int nt = 0; nt < NT; ++nt)
        bb[0][nt] = *(const half8*)(w0sh + ((nt * 2 + 0) * 64 + lane) * 8);

    // ---------------- layer 0: x @ W_in (K=64) ----------------
#pragma unroll
    for (int ks = 0; ks < 2; ++ks) {
        const int cur = ks & 1, nxt = cur ^ 1;
        if (ks == 0) {               // prefetch ks=1
#pragma unroll
            for (int nt = 0; nt < NT; ++nt)
                bb[nxt][nt] = *(const half8*)(w0sh + ((nt * 2 + 1) * 64 + lane) * 8);
        } else {                     // prefetch hidden layer 0, ks=0
#pragma unroll
            for (int nt = 0; nt < NT; ++nt)
                bb[nxt][nt] = *(const half8*)(wsh + ((nt * 4 + 0) * 64 + lane) * 8);
        }
        half8 ahi, alo;
        split8(x + (rowbase + l15) * DIN + ks * 32 + q * 8, ahi, alo);
#pragma unroll
        for (int nt = 0; nt < NT; ++nt) {
            acc[nt] = __builtin_amdgcn_mfma_f32_16x16x32_f16(ahi, bb[cur][nt], acc[nt], 0, 0, 0);
            acc[nt] = __builtin_amdgcn_mfma_f32_16x16x32_f16(alo, bb[cur][nt], acc[nt], 0, 0, 0);
        }
    }
    // epilogue 0: bias + leaky -> LDS (cols 100..111 become exact zeros)
#pragma unroll
    for (int nt = 0; nt < NT; ++nt) {
        const int col = nt * 16 + l15;
        const float bbias = bpad[col];
#pragma unroll
        for (int r = 0; r < 4; ++r) {
            float v = acc[nt][r] + bbias;
            v = fmaxf(v, 0.01f * v);          // leaky: max(x, 0.01x)
            hlds[q * 4 + r][col] = v;
        }
    }

    // ---------------- 100 hidden layers (K=128 padded, ks=3 half-masked) ----------------
#pragma unroll 1
    for (int l = 0; l < NLAYERS; ++l) {
        const _Float16* wl = wsh + l * WSH_LAYER_HALVES;
        const _Float16* wlnext = wsh + (l < NLAYERS - 1 ? l + 1 : l) * WSH_LAYER_HALVES;
#pragma unroll
        for (int nt = 0; nt < NT; ++nt) acc[nt] = zero4;

#pragma unroll
        for (int ks = 0; ks < 4; ++ks) {
            const int cur = ks & 1, nxt = cur ^ 1;
            // prefetch next k-step (or next layer's ks=0) B frags
            const _Float16* src = (ks < 3) ? (wl + (((ks + 1)) * 64 + lane) * 8)
                                           : (wlnext + ((0) * 64 + lane) * 8);
#pragma unroll
            for (int nt = 0; nt < NT; ++nt)
                bb[nxt][nt] = *(const half8*)(src + nt * 4 * 64 * 8);

            half8 ahi, alo;
            if (ks == 3 && q >= 2) {          // k in [112,128): zero pad region (must mask!)
                ahi = zeroh; alo = zeroh;
            } else {
                split8(&hlds[l15][ks * 32 + q * 8], ahi, alo);
            }
#pragma unroll
            for (int nt = 0; nt < NT; ++nt) {
                acc[nt] = __builtin_amdgcn_mfma_f32_16x16x32_f16(ahi, bb[cur][nt], acc[nt], 0, 0, 0);
                acc[nt] = __builtin_amdgcn_mfma_f32_16x16x32_f16(alo, bb[cur][nt], acc[nt], 0, 0, 0);
            }
        }
        // epilogue: bias + leaky -> LDS (fp32, full precision carried between layers)
        const float* brow = bpad + (l + 1) * NPAD;
#pragma unroll
        for (int nt = 0; nt < NT; ++nt) {
            const int col = nt * 16 + l15;
            const float bbias = brow[col];
#pragma unroll
            for (int r = 0; r < 4; ++r) {
                float v = acc[nt][r] + bbias;
                v = fmaxf(v, 0.01f * v);
                hlds[q * 4 + r][col] = v;
            }
        }
    }

    // ---------------- head: dot(h, W_out) + b_out, tanh, affine ----------------
    {
        const int row = lane >> 2, hf = lane & 3;   // 4 lanes per row, 28 cols each
        const float* hp = &hlds[row][hf * 28];
        const float* wp = woutp + hf * 28;
        float s = 0.f;
#pragma unroll
        for (int i = 0; i < 7; ++i) {
            f32x4 hv = *(const f32x4*)(hp + i * 4);
            f32x4 wv = *(const f32x4*)(wp + i * 4);
            s += hv[0] * wv[0] + hv[1] * wv[1] + hv[2] * wv[2] + hv[3] * wv[3];
        }
        s += __shfl_xor(s, 1);
        s += __shfl_xor(s, 2);
        if (hf == 0) {
            float a = s + bout[0];
            float t = tanhf(a);
            out[rowbase + row] = t * 4.5f + 5.5f;   // (tanh+1)/2*9 + 1
        }
    }
}

extern "C" void kernel_launch(void* const* d_in, const int* in_sizes, int n_in,
                              void* d_out, int out_size, void* d_ws, size_t ws_size,
                              hipStream_t stream) {
    const float* x    = (const float*)d_in[0];
    const float* Win  = (const float*)d_in[1];
    const float* bin  = (const float*)d_in[2];
    const float* Ws   = (const float*)d_in[3];
    const float* bs   = (const float*)d_in[4];
    const float* Wout = (const float*)d_in[5];
    const float* bout = (const float*)d_in[6];
    float* out = (float*)d_out;

    char* ws = (char*)d_ws;
    _Float16* wsh  = (_Float16*)ws;
    _Float16* w0sh = wsh + WSH_HALVES;
    float* bpad  = (float*)(ws + OFF_BPAD_B);
    float* woutp = (float*)(ws + OFF_WOUT_B);

    hipLaunchKernelGGL(actor_prep, dim3((TOTAL_PREP + 255) / 256), dim3(256), 0, stream,
                       Win, bin, Ws, bs, Wout, wsh, w0sh, bpad, woutp);

    const int nrows = in_sizes[0] / DIN;   // 65536
    hipLaunchKernelGGL(actor_main, dim3(nrows / ROWS), dim3(64), 0, stream,
                       x, wsh, w0sh, bpad, woutp, bout, out);
}